// Round 3
// baseline (457.555 us; speedup 1.0000x reference)
//
#include <hip/hip_runtime.h>
#include <hip/hip_bf16.h>
#include <math.h>

// Problem constants (from reference setup_inputs)
#define P_ 4
#define B_ 128
#define D_ 512
#define N_ 32768
#define K_ 10
#define TNB 128          // n-tile per block in neg_mfma_kernel
#define NT2 (N_ / TNB)   // 256 tiles per p
#define BKC 64           // k-chunk (2 MFMA K-steps)
#define KP 72            // padded LDS row stride in shorts (64 + 8)

typedef __attribute__((ext_vector_type(8))) short bf16x8;   // 8 bf16 (4 VGPRs)
typedef __attribute__((ext_vector_type(4))) float f32x4;    // MFMA acc

static __device__ __forceinline__ float block_sum_128(float v, float* sh) {
    const int t = threadIdx.x;
    sh[t] = v; __syncthreads();
    #pragma unroll
    for (int s = 64; s > 0; s >>= 1) { if (t < s) sh[t] += sh[t + s]; __syncthreads(); }
    float r = sh[0]; __syncthreads();
    return r;
}

static __device__ __forceinline__ uint2 pack_bf16x4(float4 v) {
    union { __hip_bfloat162 h; unsigned u; } lo, hi;
    lo.h = __float22bfloat162_rn(make_float2(v.x, v.y));   // RNE
    hi.h = __float22bfloat162_rn(make_float2(v.z, v.w));
    uint2 r; r.x = lo.u; r.y = hi.u;
    return r;
}

// ---------- prep: feature -> bf16 (for direct A-fragment loads) + mask init ----------
__global__ void prep_kernel(const float* __restrict__ feature,
                            unsigned short* __restrict__ featbf,
                            float* __restrict__ maskf) {
    int i = blockIdx.x * 256 + threadIdx.x;       // 0..65535 (P*B*D/4)
    float4 v = ((const float4*)feature)[i];
    ((uint2*)featbf)[i] = pack_bf16x4(v);
    if (i < N_) maskf[i] = 1.0f;
}

__global__ void mask_zero_kernel(const int* __restrict__ cross,
                                 const int* __restrict__ pos,
                                 float* __restrict__ m) {
    int i = blockIdx.x * 256 + threadIdx.x;
    if (i < B_ * K_) m[cross[i]] = 0.0f;
    else if (i < B_ * K_ + B_) m[pos[i - B_ * K_]] = 0.0f;
}

// ---------- normalize feature -> img, text_feature^T -> txt; fn2 = ||feature||^2 ----------
__global__ void norm_kernel(const float* __restrict__ feature,
                            const float* __restrict__ text_feature,
                            float* __restrict__ img, float* __restrict__ txt,
                            float* __restrict__ fn2) {
    const int pb = blockIdx.x;            // p*B + b
    const int p = pb >> 7, b = pb & 127;
    const int which = blockIdx.y;         // 0 = img (from feature), 1 = txt (from text_feature)
    const int t = threadIdx.x;            // 256 threads, 2 elems each
    const float* src = (which == 0) ? feature + (size_t)pb * D_
                                    : text_feature + ((size_t)b * P_ + p) * D_;
    float v0 = src[t], v1 = src[t + 256];
    __shared__ float sred[256];
    sred[t] = v0 * v0 + v1 * v1;
    __syncthreads();
    #pragma unroll
    for (int s = 128; s > 0; s >>= 1) { if (t < s) sred[t] += sred[t + s]; __syncthreads(); }
    const float ss = sred[0];
    const float inv = 1.0f / fmaxf(sqrtf(ss), 1e-12f);
    float* dst = (which == 0) ? img : txt;
    dst[(size_t)pb * D_ + t] = v0 * inv;
    dst[(size_t)pb * D_ + t + 256] = v1 * inv;
    if (which == 0 && t == 0) fn2[pb] = ss;
}

// ---------- img_sim/txt_sim (P,B,B) and valid (any over columns of mask) ----------
__global__ void sim_kernel(const float* __restrict__ img,
                           const float* __restrict__ txt,
                           float* __restrict__ img_sim,
                           float* __restrict__ txt_sim,
                           float* __restrict__ validf) {
    const int p = blockIdx.x;
    const int b0 = blockIdx.y * 2;        // 2 rows per block
    const int c = threadIdx.x;            // 128 threads, one column each
    __shared__ float ai[2][D_];
    __shared__ float at[2][D_];
    __shared__ int flags[2];
    #pragma unroll
    for (int i = 0; i < 8; ++i) {
        int idx = c + i * 128;            // 0..1023
        int row = idx >> 9, d = idx & 511;
        ai[row][d] = img[(size_t)(p * B_ + b0 + row) * D_ + d];
        at[row][d] = txt[(size_t)(p * B_ + b0 + row) * D_ + d];
    }
    if (c < 2) flags[c] = 0;
    __syncthreads();
    float di[2] = {0, 0};
    float dt[2] = {0, 0};
    const float* ic = img + (size_t)(p * B_ + c) * D_;
    const float* tc = txt + (size_t)(p * B_ + c) * D_;
    for (int d = 0; d < D_; d += 4) {
        float4 vi = *(const float4*)(ic + d);
        float4 vt = *(const float4*)(tc + d);
        #pragma unroll
        for (int i = 0; i < 2; ++i) {
            di[i] += ai[i][d] * vi.x + ai[i][d + 1] * vi.y + ai[i][d + 2] * vi.z + ai[i][d + 3] * vi.w;
            dt[i] += at[i][d] * vt.x + at[i][d + 1] * vt.y + at[i][d + 2] * vt.z + at[i][d + 3] * vt.w;
        }
    }
    #pragma unroll
    for (int i = 0; i < 2; ++i) {
        float is = 2.0f * di[i];          // / TEMP (0.5)
        float ts = 2.0f * dt[i];
        img_sim[(size_t)(p * B_ + b0 + i) * B_ + c] = is;
        txt_sim[(size_t)(p * B_ + b0 + i) * B_ + c] = ts;
        if (is > 0.7f && ts > 0.7f) flags[i] = 1;   // benign write race
    }
    __syncthreads();
    if (c < 2) validf[p * B_ + b0 + c] = (float)flags[c];
}

// ---------- per-row masked log-softmax + symmetric KL (one wave per row) ----------
__global__ __launch_bounds__(256) void kl_kernel(
    const float* __restrict__ img_sim,
    const float* __restrict__ txt_sim,
    const float* __restrict__ validf,
    float* __restrict__ klrow) {
    const int l = threadIdx.x & 63;
    const int wv = threadIdx.x >> 6;
    const int p = blockIdx.x;
    const int r = blockIdx.y * 4 + wv;
    const size_t base = (size_t)(p * B_ + r) * B_;
    const bool v0 = validf[p * B_ + l] > 0.5f;
    const bool v1 = validf[p * B_ + 64 + l] > 0.5f;
    const float il0 = v0 ? img_sim[base + l] : -1e30f;
    const float il1 = v1 ? img_sim[base + 64 + l] : -1e30f;
    const float tl0 = v0 ? txt_sim[base + l] : -1e30f;
    const float tl1 = v1 ? txt_sim[base + 64 + l] : -1e30f;
    float mi = fmaxf(il0, il1), mt = fmaxf(tl0, tl1);
    #pragma unroll
    for (int off = 32; off > 0; off >>= 1) {
        mi = fmaxf(mi, __shfl_xor(mi, off));
        mt = fmaxf(mt, __shfl_xor(mt, off));
    }
    float si = expf(il0 - mi) + expf(il1 - mi);
    float st = expf(tl0 - mt) + expf(tl1 - mt);
    #pragma unroll
    for (int off = 32; off > 0; off >>= 1) {
        si += __shfl_xor(si, off);
        st += __shfl_xor(st, off);
    }
    const float lsei = mi + logf(si);
    const float lset = mt + logf(st);
    float term = 0.0f;
    if (v0) {
        float lpi = il0 - lsei, lpt = tl0 - lset;
        term += expf(lpt) * (lpt - lpi) + expf(lpi) * (lpi - lpt);
    }
    if (v1) {
        float lpi = il1 - lsei, lpt = tl1 - lset;
        term += expf(lpt) * (lpt - lpi) + expf(lpi) * (lpi - lpt);
    }
    #pragma unroll
    for (int off = 32; off > 0; off >>= 1) term += __shfl_xor(term, off);
    if (l == 0) klrow[p * B_ + r] = (validf[p * B_ + r] > 0.5f) ? term : 0.0f;
}

// ---------- x[p,b] = log sum_k exp(-SCALE * pos_dist) ----------
__global__ void posx_kernel(const float* __restrict__ feature,
                            const float* __restrict__ centers,
                            const float* __restrict__ fn2,
                            const int* __restrict__ cross,
                            float* __restrict__ xarr) {
    const int pb = blockIdx.x;
    const int p = pb >> 7, b = pb & 127;
    const int l = threadIdx.x;            // 64 (one wave)
    const float* f = feature + (size_t)pb * D_;
    float4 f0 = *(const float4*)(f + l * 4);
    float4 f1 = *(const float4*)(f + 256 + l * 4);
    const float fn2v = fn2[pb];
    float ex = 0.0f;
    #pragma unroll
    for (int k = 0; k < K_; ++k) {
        int idx = cross[b * K_ + k];
        const float* cp = centers + ((size_t)p * N_ + idx) * D_;
        float4 c0 = *(const float4*)(cp + l * 4);
        float4 c1 = *(const float4*)(cp + 256 + l * 4);
        float dot = f0.x * c0.x + f0.y * c0.y + f0.z * c0.z + f0.w * c0.w
                  + f1.x * c1.x + f1.y * c1.y + f1.z * c1.z + f1.w * c1.w;
        float pn2 = c0.x * c0.x + c0.y * c0.y + c0.z * c0.z + c0.w * c0.w
                  + c1.x * c1.x + c1.y * c1.y + c1.z * c1.z + c1.w * c1.w;
        #pragma unroll
        for (int off = 32; off > 0; off >>= 1) {
            dot += __shfl_down(dot, off);
            pn2 += __shfl_down(pn2, off);
        }
        if (l == 0) {
            float d2 = fn2v + pn2 - 2.0f * dot;
            ex += expf(-10.0f * sqrtf(fmaxf(d2, 1e-12f)));
        }
    }
    if (l == 0) xarr[pb] = logf(ex);
}

// ---------- main kernel: bf16 MFMA GEMM + fused sqrt/exp/mask epilogue ----------
// A (feature) fragments load directly from global bf16 (L2-hot, pre-converted).
// B (centers) staged fp32->bf16 through double-buffered LDS, 1 sync/chunk.
// cn2 exact fp32, lane-local accumulation, one end-of-loop shuffle reduce.
__global__ __launch_bounds__(256) void neg_mfma_kernel(
    const unsigned short* __restrict__ featbf,
    const float* __restrict__ centers,
    const float* __restrict__ fn2,
    const float* __restrict__ maskf,
    float* __restrict__ Spart) {
    const int tile = blockIdx.x;          // 0..NT2-1
    const int p = blockIdx.y;
    const int n0g = tile * TNB;
    const int t = threadIdx.x;
    const int l = t & 63;                 // lane
    const int w = t >> 6;                 // wave 0..3
    const int m0w = (w & 1) * 64;         // wave m-offset (b)
    const int n0w = (w >> 1) * 64;        // wave n-offset

    __shared__ unsigned short Bs[2][128 * KP];   // centers tile, bf16, double-buffered
    __shared__ float cn2s[128];
    __shared__ float red[128];
    __shared__ float fn2s[128];

    if (t < 128) { red[t] = 0.0f; fn2s[t] = fn2[p * B_ + t]; }

    f32x4 acc[4][4];
    #pragma unroll
    for (int i = 0; i < 4; ++i)
        #pragma unroll
        for (int j = 0; j < 4; ++j) acc[i][j] = (f32x4)0.0f;

    float c2acc[8];
    #pragma unroll
    for (int i = 0; i < 8; ++i) c2acc[i] = 0.0f;

    const unsigned short* Ab = featbf + (size_t)p * B_ * D_;
    const float* Bb = centers + ((size_t)p * N_ + n0g) * D_;

    const int lrow = t >> 4;              // 0..15 (staging row group)
    const int c4 = t & 15;                // float4 slot within a 64-float row chunk

    // preload + stage chunk 0 into buf 0
    float4 vb[8];
    #pragma unroll
    for (int i = 0; i < 8; ++i)
        vb[i] = *(const float4*)(Bb + (size_t)(lrow + i * 16) * D_ + c4 * 4);
    #pragma unroll
    for (int i = 0; i < 8; ++i) {
        const int row = lrow + i * 16;
        *(uint2*)&Bs[0][row * KP + c4 * 4] = pack_bf16x4(vb[i]);
        c2acc[i] += vb[i].x * vb[i].x + vb[i].y * vb[i].y
                  + vb[i].z * vb[i].z + vb[i].w * vb[i].w;
    }
    __syncthreads();

    for (int kk = 0; kk < D_; kk += BKC) {
        const int cur = (kk >> 6) & 1;
        const int nxt = cur ^ 1;
        const bool more = (kk + BKC) < D_;
        if (more) {
            #pragma unroll
            for (int i = 0; i < 8; ++i)
                vb[i] = *(const float4*)(Bb + (size_t)(lrow + i * 16) * D_ + (kk + BKC) + c4 * 4);
        }
        #pragma unroll
        for (int ks = 0; ks < 2; ++ks) {
            bf16x8 af[4], bfr[4];
            const int ko = ks * 32 + (l >> 4) * 8;
            #pragma unroll
            for (int i = 0; i < 4; ++i) {
                af[i]  = *(const bf16x8*)(Ab + (size_t)(m0w + i * 16 + (l & 15)) * D_ + kk + ko);
                bfr[i] = *(const bf16x8*)&Bs[cur][(n0w + i * 16 + (l & 15)) * KP + ko];
            }
            #pragma unroll
            for (int i = 0; i < 4; ++i)
                #pragma unroll
                for (int j = 0; j < 4; ++j)
                    acc[i][j] = __builtin_amdgcn_mfma_f32_16x16x32_bf16(
                        af[i], bfr[j], acc[i][j], 0, 0, 0);
        }
        if (more) {
            #pragma unroll
            for (int i = 0; i < 8; ++i) {
                const int row = lrow + i * 16;
                *(uint2*)&Bs[nxt][row * KP + c4 * 4] = pack_bf16x4(vb[i]);
                c2acc[i] += vb[i].x * vb[i].x + vb[i].y * vb[i].y
                          + vb[i].z * vb[i].z + vb[i].w * vb[i].w;
            }
        }
        __syncthreads();
    }

    // cn2: reduce lane-local partials across the 16 c4 lanes of each row group
    #pragma unroll
    for (int i = 0; i < 8; ++i) {
        float s = c2acc[i];
        s += __shfl_xor(s, 1); s += __shfl_xor(s, 2);
        s += __shfl_xor(s, 4); s += __shfl_xor(s, 8);
        if (c4 == 0) cn2s[lrow + i * 16] = s;
    }
    __syncthreads();

    // epilogue: C/D layout col=lane&15 (n), row=(lane>>4)*4+reg (b)  [m89/m91]
    float c2l[4], mkl[4];
    #pragma unroll
    for (int j = 0; j < 4; ++j) {
        const int col = n0w + j * 16 + (l & 15);
        c2l[j] = cn2s[col];
        mkl[j] = maskf[n0g + col];
    }
    #pragma unroll
    for (int i = 0; i < 4; ++i) {
        #pragma unroll
        for (int r = 0; r < 4; ++r) {
            const int row = m0w + i * 16 + (l >> 4) * 4 + r;
            const float fv = fn2s[row];
            float s = 0.0f;
            #pragma unroll
            for (int j = 0; j < 4; ++j) {
                const float nd2 = fv + c2l[j] - 2.0f * acc[i][j][r];
                s += mkl[j] * __expf(-10.0f * sqrtf(fmaxf(nd2, 1e-12f)));
            }
            s += __shfl_xor(s, 1); s += __shfl_xor(s, 2);
            s += __shfl_xor(s, 4); s += __shfl_xor(s, 8);
            if ((l & 15) == 0) atomicAdd(&red[row], s);   // LDS atomic, 2 adds/row
        }
    }
    __syncthreads();
    if (t < 128) Spart[(size_t)(p * B_ + t) * NT2 + tile] = red[t];
}

// ---------- reduce tile partials: diff[p,b] = log(S) - x ----------
__global__ void red_kernel(const float* __restrict__ Spart,
                           const float* __restrict__ xarr,
                           float* __restrict__ diff) {
    const int pb = blockIdx.x;
    const int t = threadIdx.x;            // 128
    __shared__ float sh[128];
    const float* sp = Spart + (size_t)pb * NT2;
    float s = sp[t] + sp[t + 128];
    float S = block_sum_128(s, sh);
    if (t == 0) diff[pb] = logf(S) - xarr[pb];
}

// ---------- final scalars ----------
__global__ void final_kernel(const float* __restrict__ validf,
                             const float* __restrict__ klrow,
                             const float* __restrict__ diff,
                             float* __restrict__ out) {
    const int t = threadIdx.x;            // 128
    __shared__ float sh[128];
    __shared__ float accum[2];            // [0]=contrastive sum over p, [1]=align
    if (t == 0) { accum[0] = 0.0f; accum[1] = 0.0f; }
    __syncthreads();
    for (int p = 0; p < P_; ++p) {
        float nv = block_sum_128(validf[p * B_ + t], sh);
        float ks = block_sum_128(klrow[p * B_ + t], sh);
        float ds = block_sum_128(diff[p * B_ + t], sh);
        if (t == 0) {
            float lp = ds / (float)B_;
            if (!(lp != lp)) accum[0] += lp;                    // where(isnan, 0)
            if (nv > 0.5f) accum[1] += 0.5f * ks / fmaxf(nv, 1.0f);
        }
        __syncthreads();
    }
    if (t == 0) {
        float contrastive = accum[0] / (float)P_;
        float align = accum[1];
        out[1] = contrastive;
        out[2] = align;
        // KL_WEIGHT = max(0.5*(1 - 1/60), 0.1)
        out[0] = contrastive + 0.49166666666666664f * align;
    }
}

// ---------- pos_vid gather ----------
__global__ void posvid_kernel(const int* __restrict__ cross,
                              const int* __restrict__ vid,
                              float* __restrict__ out) {
    int i = blockIdx.x * 256 + threadIdx.x;
    if (i < B_ * K_) out[3 + i] = (float)vid[cross[i]];
}

extern "C" void kernel_launch(void* const* d_in, const int* in_sizes, int n_in,
                              void* d_out, int out_size, void* d_ws, size_t ws_size,
                              hipStream_t stream) {
    const float* feature      = (const float*)d_in[0];
    const float* text_feature = (const float*)d_in[1];
    const float* centers      = (const float*)d_in[2];
    const int*   position     = (const int*)d_in[3];
    const int*   cross        = (const int*)d_in[4];
    const int*   vid          = (const int*)d_in[5];
    float* out = (float*)d_out;

    // workspace layout (floats)
    float* ws      = (float*)d_ws;
    float* img     = ws;                                  // P*B*D
    float* txt     = img + (size_t)P_ * B_ * D_;          // P*B*D
    float* fn2     = txt + (size_t)P_ * B_ * D_;          // P*B
    float* img_sim = fn2 + P_ * B_;                       // P*B*B
    float* txt_sim = img_sim + P_ * B_ * B_;              // P*B*B
    float* validf  = txt_sim + P_ * B_ * B_;              // P*B
    float* klrow   = validf + P_ * B_;                    // P*B
    float* xarr    = klrow + P_ * B_;                     // P*B
    float* maskf   = xarr + P_ * B_;                      // N
    float* diff    = maskf + N_;                          // P*B
    float* Spart   = diff + P_ * B_;                      // P*B*NT2
    unsigned short* featbf = (unsigned short*)(Spart + (size_t)P_ * B_ * NT2);  // P*B*D bf16

    prep_kernel<<<P_ * B_ * D_ / 4 / 256, 256, 0, stream>>>(feature, featbf, maskf);
    mask_zero_kernel<<<(B_ * K_ + B_ + 255) / 256, 256, 0, stream>>>(cross, position, maskf);
    norm_kernel<<<dim3(P_ * B_, 2), 256, 0, stream>>>(feature, text_feature, img, txt, fn2);
    sim_kernel<<<dim3(P_, B_ / 2), 128, 0, stream>>>(img, txt, img_sim, txt_sim, validf);
    kl_kernel<<<dim3(P_, B_ / 4), 256, 0, stream>>>(img_sim, txt_sim, validf, klrow);
    posx_kernel<<<P_ * B_, 64, 0, stream>>>(feature, centers, fn2, cross, xarr);
    neg_mfma_kernel<<<dim3(NT2, P_), 256, 0, stream>>>(featbf, centers, fn2, maskf, Spart);
    red_kernel<<<P_ * B_, 128, 0, stream>>>(Spart, xarr, diff);
    final_kernel<<<1, 128, 0, stream>>>(validf, klrow, diff, out);
    posvid_kernel<<<(B_ * K_ + 255) / 256, 256, 0, stream>>>(cross, vid, out);
}

// Round 4
// 446.614 us; speedup vs baseline: 1.0245x; 1.0245x over previous
//
#include <hip/hip_runtime.h>
#include <hip/hip_bf16.h>
#include <math.h>

// Problem constants (from reference setup_inputs)
#define P_ 4
#define B_ 128
#define D_ 512
#define N_ 32768
#define K_ 10
#define TNB 128          // n-tile per block in neg_mfma_kernel
#define NT2 (N_ / TNB)   // 256 tiles per p
#define BK2 32           // k-chunk (1 MFMA K-step)
#define NCH (D_ / BK2)   // 16 chunks
#define KP2 40           // padded LDS row stride in shorts (32 + 8)

typedef __attribute__((ext_vector_type(8))) short bf16x8;   // 8 bf16 (4 VGPRs)
typedef __attribute__((ext_vector_type(4))) float f32x4;    // MFMA acc

static __device__ __forceinline__ float block_sum_128(float v, float* sh) {
    const int t = threadIdx.x;
    sh[t] = v; __syncthreads();
    #pragma unroll
    for (int s = 64; s > 0; s >>= 1) { if (t < s) sh[t] += sh[t + s]; __syncthreads(); }
    float r = sh[0]; __syncthreads();
    return r;
}

static __device__ __forceinline__ uint2 pack_bf16x4(float4 v) {
    union { __hip_bfloat162 h; unsigned u; } lo, hi;
    lo.h = __float22bfloat162_rn(make_float2(v.x, v.y));   // RNE
    hi.h = __float22bfloat162_rn(make_float2(v.z, v.w));
    uint2 r; r.x = lo.u; r.y = hi.u;
    return r;
}

// ---------- mask init ----------
__global__ void mask_init_kernel(float* __restrict__ m) {
    int i = blockIdx.x * 256 + threadIdx.x;
    if (i < N_) m[i] = 1.0f;
}
__global__ void mask_zero_kernel(const int* __restrict__ cross,
                                 const int* __restrict__ pos,
                                 float* __restrict__ m) {
    int i = blockIdx.x * 256 + threadIdx.x;
    if (i < B_ * K_) m[cross[i]] = 0.0f;
    else if (i < B_ * K_ + B_) m[pos[i - B_ * K_]] = 0.0f;
}

// ---------- normalize feature -> img, text_feature^T -> txt; fn2 = ||feature||^2 ----------
__global__ void norm_kernel(const float* __restrict__ feature,
                            const float* __restrict__ text_feature,
                            float* __restrict__ img, float* __restrict__ txt,
                            float* __restrict__ fn2) {
    const int pb = blockIdx.x;            // p*B + b
    const int p = pb >> 7, b = pb & 127;
    const int which = blockIdx.y;         // 0 = img (from feature), 1 = txt (from text_feature)
    const int t = threadIdx.x;            // 256 threads, 2 elems each
    const float* src = (which == 0) ? feature + (size_t)pb * D_
                                    : text_feature + ((size_t)b * P_ + p) * D_;
    float v0 = src[t], v1 = src[t + 256];
    __shared__ float sred[256];
    sred[t] = v0 * v0 + v1 * v1;
    __syncthreads();
    #pragma unroll
    for (int s = 128; s > 0; s >>= 1) { if (t < s) sred[t] += sred[t + s]; __syncthreads(); }
    const float ss = sred[0];
    const float inv = 1.0f / fmaxf(sqrtf(ss), 1e-12f);
    float* dst = (which == 0) ? img : txt;
    dst[(size_t)pb * D_ + t] = v0 * inv;
    dst[(size_t)pb * D_ + t + 256] = v1 * inv;
    if (which == 0 && t == 0) fn2[pb] = ss;
}

// ---------- img_sim/txt_sim (P,B,B) and valid (any over columns of mask) ----------
__global__ void sim_kernel(const float* __restrict__ img,
                           const float* __restrict__ txt,
                           float* __restrict__ img_sim,
                           float* __restrict__ txt_sim,
                           float* __restrict__ validf) {
    const int p = blockIdx.x;
    const int b0 = blockIdx.y * 2;        // 2 rows per block
    const int c = threadIdx.x;            // 128 threads, one column each
    __shared__ float ai[2][D_];
    __shared__ float at[2][D_];
    __shared__ int flags[2];
    #pragma unroll
    for (int i = 0; i < 8; ++i) {
        int idx = c + i * 128;            // 0..1023
        int row = idx >> 9, d = idx & 511;
        ai[row][d] = img[(size_t)(p * B_ + b0 + row) * D_ + d];
        at[row][d] = txt[(size_t)(p * B_ + b0 + row) * D_ + d];
    }
    if (c < 2) flags[c] = 0;
    __syncthreads();
    float di[2] = {0, 0};
    float dt[2] = {0, 0};
    const float* ic = img + (size_t)(p * B_ + c) * D_;
    const float* tc = txt + (size_t)(p * B_ + c) * D_;
    for (int d = 0; d < D_; d += 4) {
        float4 vi = *(const float4*)(ic + d);
        float4 vt = *(const float4*)(tc + d);
        #pragma unroll
        for (int i = 0; i < 2; ++i) {
            di[i] += ai[i][d] * vi.x + ai[i][d + 1] * vi.y + ai[i][d + 2] * vi.z + ai[i][d + 3] * vi.w;
            dt[i] += at[i][d] * vt.x + at[i][d + 1] * vt.y + at[i][d + 2] * vt.z + at[i][d + 3] * vt.w;
        }
    }
    #pragma unroll
    for (int i = 0; i < 2; ++i) {
        float is = 2.0f * di[i];          // / TEMP (0.5)
        float ts = 2.0f * dt[i];
        img_sim[(size_t)(p * B_ + b0 + i) * B_ + c] = is;
        txt_sim[(size_t)(p * B_ + b0 + i) * B_ + c] = ts;
        if (is > 0.7f && ts > 0.7f) flags[i] = 1;   // benign write race
    }
    __syncthreads();
    if (c < 2) validf[p * B_ + b0 + c] = (float)flags[c];
}

// ---------- per-row masked log-softmax + symmetric KL (one wave per row) ----------
__global__ __launch_bounds__(256) void kl_kernel(
    const float* __restrict__ img_sim,
    const float* __restrict__ txt_sim,
    const float* __restrict__ validf,
    float* __restrict__ klrow) {
    const int l = threadIdx.x & 63;
    const int wv = threadIdx.x >> 6;
    const int p = blockIdx.x;
    const int r = blockIdx.y * 4 + wv;
    const size_t base = (size_t)(p * B_ + r) * B_;
    const bool v0 = validf[p * B_ + l] > 0.5f;
    const bool v1 = validf[p * B_ + 64 + l] > 0.5f;
    const float il0 = v0 ? img_sim[base + l] : -1e30f;
    const float il1 = v1 ? img_sim[base + 64 + l] : -1e30f;
    const float tl0 = v0 ? txt_sim[base + l] : -1e30f;
    const float tl1 = v1 ? txt_sim[base + 64 + l] : -1e30f;
    float mi = fmaxf(il0, il1), mt = fmaxf(tl0, tl1);
    #pragma unroll
    for (int off = 32; off > 0; off >>= 1) {
        mi = fmaxf(mi, __shfl_xor(mi, off));
        mt = fmaxf(mt, __shfl_xor(mt, off));
    }
    float si = expf(il0 - mi) + expf(il1 - mi);
    float st = expf(tl0 - mt) + expf(tl1 - mt);
    #pragma unroll
    for (int off = 32; off > 0; off >>= 1) {
        si += __shfl_xor(si, off);
        st += __shfl_xor(st, off);
    }
    const float lsei = mi + logf(si);
    const float lset = mt + logf(st);
    float term = 0.0f;
    if (v0) {
        float lpi = il0 - lsei, lpt = tl0 - lset;
        term += expf(lpt) * (lpt - lpi) + expf(lpi) * (lpi - lpt);
    }
    if (v1) {
        float lpi = il1 - lsei, lpt = tl1 - lset;
        term += expf(lpt) * (lpt - lpi) + expf(lpi) * (lpi - lpt);
    }
    #pragma unroll
    for (int off = 32; off > 0; off >>= 1) term += __shfl_xor(term, off);
    if (l == 0) klrow[p * B_ + r] = (validf[p * B_ + r] > 0.5f) ? term : 0.0f;
}

// ---------- x[p,b] = log sum_k exp(-SCALE * pos_dist) ----------
__global__ void posx_kernel(const float* __restrict__ feature,
                            const float* __restrict__ centers,
                            const float* __restrict__ fn2,
                            const int* __restrict__ cross,
                            float* __restrict__ xarr) {
    const int pb = blockIdx.x;
    const int p = pb >> 7, b = pb & 127;
    const int l = threadIdx.x;            // 64 (one wave)
    const float* f = feature + (size_t)pb * D_;
    float4 f0 = *(const float4*)(f + l * 4);
    float4 f1 = *(const float4*)(f + 256 + l * 4);
    const float fn2v = fn2[pb];
    float ex = 0.0f;
    #pragma unroll
    for (int k = 0; k < K_; ++k) {
        int idx = cross[b * K_ + k];
        const float* cp = centers + ((size_t)p * N_ + idx) * D_;
        float4 c0 = *(const float4*)(cp + l * 4);
        float4 c1 = *(const float4*)(cp + 256 + l * 4);
        float dot = f0.x * c0.x + f0.y * c0.y + f0.z * c0.z + f0.w * c0.w
                  + f1.x * c1.x + f1.y * c1.y + f1.z * c1.z + f1.w * c1.w;
        float pn2 = c0.x * c0.x + c0.y * c0.y + c0.z * c0.z + c0.w * c0.w
                  + c1.x * c1.x + c1.y * c1.y + c1.z * c1.z + c1.w * c1.w;
        #pragma unroll
        for (int off = 32; off > 0; off >>= 1) {
            dot += __shfl_down(dot, off);
            pn2 += __shfl_down(pn2, off);
        }
        if (l == 0) {
            float d2 = fn2v + pn2 - 2.0f * dot;
            ex += expf(-10.0f * sqrtf(fmaxf(d2, 1e-12f)));
        }
    }
    if (l == 0) xarr[pb] = logf(ex);
}

// ---------- main kernel: bf16 MFMA GEMM + fused sqrt/exp/mask epilogue ----------
// BOTH A and B fragments come from LDS (lgkmcnt) so the global prefetch (vmcnt)
// is only waited at the pack step — no vmcnt aliasing with MFMA operand loads.
// Double-buffered As/Bs, BK=32, 1 barrier per chunk, 16 chunks.
__global__ __launch_bounds__(256) void neg_mfma_kernel(
    const float* __restrict__ feature,
    const float* __restrict__ centers,
    const float* __restrict__ fn2,
    const float* __restrict__ maskf,
    float* __restrict__ Spart) {
    const int tile = blockIdx.x;          // 0..NT2-1
    const int p = blockIdx.y;
    const int n0g = tile * TNB;
    const int t = threadIdx.x;
    const int l = t & 63;                 // lane
    const int w = t >> 6;                 // wave 0..3
    const int m0w = (w & 1) * 64;         // wave m-offset (b)
    const int n0w = (w >> 1) * 64;        // wave n-offset

    __shared__ unsigned short As[2][128 * KP2];   // feature tile, bf16, dbuf
    __shared__ unsigned short Bs[2][128 * KP2];   // centers tile, bf16, dbuf
    __shared__ float cn2s[128];
    __shared__ float red[128];
    __shared__ float fn2s[128];

    if (t < 128) { red[t] = 0.0f; fn2s[t] = fn2[p * B_ + t]; }

    f32x4 acc[4][4];
    #pragma unroll
    for (int i = 0; i < 4; ++i)
        #pragma unroll
        for (int j = 0; j < 4; ++j) acc[i][j] = (f32x4)0.0f;

    float c2acc[4] = {0.0f, 0.0f, 0.0f, 0.0f};

    const float* Ab = feature + (size_t)p * B_ * D_;
    const float* Bb = centers + ((size_t)p * N_ + n0g) * D_;

    const int f8 = t & 7;                 // which float4 within a 32-float row chunk
    const int r0 = t >> 3;                // 0..31; rows r0 + 32*i

    // preload + stage chunk 0 into buf 0
    float4 va[4], vb[4];
    #pragma unroll
    for (int i = 0; i < 4; ++i) {
        const int row = r0 + 32 * i;
        va[i] = *(const float4*)(Ab + (size_t)row * D_ + f8 * 4);
        vb[i] = *(const float4*)(Bb + (size_t)row * D_ + f8 * 4);
    }
    #pragma unroll
    for (int i = 0; i < 4; ++i) {
        const int row = r0 + 32 * i;
        *(uint2*)&As[0][row * KP2 + f8 * 4] = pack_bf16x4(va[i]);
        *(uint2*)&Bs[0][row * KP2 + f8 * 4] = pack_bf16x4(vb[i]);
        c2acc[i] += vb[i].x * vb[i].x + vb[i].y * vb[i].y
                  + vb[i].z * vb[i].z + vb[i].w * vb[i].w;
    }
    __syncthreads();

    const int ko = (l >> 4) * 8;          // frag k-offset in shorts (quad covers k 0..31)
    for (int c = 0; c < NCH; ++c) {
        const int cur = c & 1, nxt = cur ^ 1;
        const int kk = (c + 1) * BK2;
        if (c < NCH - 1) {
            #pragma unroll
            for (int i = 0; i < 4; ++i) {
                const int row = r0 + 32 * i;
                va[i] = *(const float4*)(Ab + (size_t)row * D_ + kk + f8 * 4);
                vb[i] = *(const float4*)(Bb + (size_t)row * D_ + kk + f8 * 4);
            }
        }
        bf16x8 af[4], bfr[4];
        #pragma unroll
        for (int i = 0; i < 4; ++i) {
            af[i]  = *(const bf16x8*)&As[cur][(m0w + i * 16 + (l & 15)) * KP2 + ko];
            bfr[i] = *(const bf16x8*)&Bs[cur][(n0w + i * 16 + (l & 15)) * KP2 + ko];
        }
        #pragma unroll
        for (int i = 0; i < 4; ++i)
            #pragma unroll
            for (int j = 0; j < 4; ++j)
                acc[i][j] = __builtin_amdgcn_mfma_f32_16x16x32_bf16(
                    af[i], bfr[j], acc[i][j], 0, 0, 0);
        if (c < NCH - 1) {
            #pragma unroll
            for (int i = 0; i < 4; ++i) {
                const int row = r0 + 32 * i;
                *(uint2*)&As[nxt][row * KP2 + f8 * 4] = pack_bf16x4(va[i]);
                *(uint2*)&Bs[nxt][row * KP2 + f8 * 4] = pack_bf16x4(vb[i]);
                c2acc[i] += vb[i].x * vb[i].x + vb[i].y * vb[i].y
                          + vb[i].z * vb[i].z + vb[i].w * vb[i].w;
            }
        }
        __syncthreads();
    }

    // cn2: reduce lane-local partials across the 8 f8 lanes of each row
    #pragma unroll
    for (int i = 0; i < 4; ++i) {
        float s = c2acc[i];
        s += __shfl_xor(s, 1); s += __shfl_xor(s, 2); s += __shfl_xor(s, 4);
        if (f8 == 0) cn2s[r0 + 32 * i] = s;
    }
    __syncthreads();

    // epilogue: C/D layout col=lane&15 (n), row=(lane>>4)*4+reg (b)  [m89/m91]
    float c2l[4], mkl[4];
    #pragma unroll
    for (int j = 0; j < 4; ++j) {
        const int col = n0w + j * 16 + (l & 15);
        c2l[j] = cn2s[col];
        mkl[j] = maskf[n0g + col];
    }
    #pragma unroll
    for (int i = 0; i < 4; ++i) {
        #pragma unroll
        for (int r = 0; r < 4; ++r) {
            const int row = m0w + i * 16 + (l >> 4) * 4 + r;
            const float fv = fn2s[row];
            float s = 0.0f;
            #pragma unroll
            for (int j = 0; j < 4; ++j) {
                const float nd2 = fv + c2l[j] - 2.0f * acc[i][j][r];
                s += mkl[j] * __expf(-10.0f * sqrtf(fmaxf(nd2, 1e-12f)));
            }
            s += __shfl_xor(s, 1); s += __shfl_xor(s, 2);
            s += __shfl_xor(s, 4); s += __shfl_xor(s, 8);
            if ((l & 15) == 0) atomicAdd(&red[row], s);   // LDS atomic, 2 adds/row
        }
    }
    __syncthreads();
    if (t < 128) Spart[(size_t)(p * B_ + t) * NT2 + tile] = red[t];
}

// ---------- reduce tile partials: diff[p,b] = log(S) - x ----------
__global__ void red_kernel(const float* __restrict__ Spart,
                           const float* __restrict__ xarr,
                           float* __restrict__ diff) {
    const int pb = blockIdx.x;
    const int t = threadIdx.x;            // 128
    __shared__ float sh[128];
    const float* sp = Spart + (size_t)pb * NT2;
    float s = sp[t] + sp[t + 128];
    float S = block_sum_128(s, sh);
    if (t == 0) diff[pb] = logf(S) - xarr[pb];
}

// ---------- final scalars + pos_vid gather ----------
__global__ void final_kernel(const float* __restrict__ validf,
                             const float* __restrict__ klrow,
                             const float* __restrict__ diff,
                             const int* __restrict__ cross,
                             const int* __restrict__ vid,
                             float* __restrict__ out) {
    const int t = threadIdx.x;            // 128
    __shared__ float sh[128];
    __shared__ float accum[2];            // [0]=contrastive sum over p, [1]=align
    if (t == 0) { accum[0] = 0.0f; accum[1] = 0.0f; }
    __syncthreads();
    for (int p = 0; p < P_; ++p) {
        float nv = block_sum_128(validf[p * B_ + t], sh);
        float ks = block_sum_128(klrow[p * B_ + t], sh);
        float ds = block_sum_128(diff[p * B_ + t], sh);
        if (t == 0) {
            float lp = ds / (float)B_;
            if (!(lp != lp)) accum[0] += lp;                    // where(isnan, 0)
            if (nv > 0.5f) accum[1] += 0.5f * ks / fmaxf(nv, 1.0f);
        }
        __syncthreads();
    }
    if (t == 0) {
        float contrastive = accum[0] / (float)P_;
        float align = accum[1];
        out[1] = contrastive;
        out[2] = align;
        // KL_WEIGHT = max(0.5*(1 - 1/60), 0.1)
        out[0] = contrastive + 0.49166666666666664f * align;
    }
    #pragma unroll
    for (int k = 0; k < K_; ++k) {
        const int i = k * 128 + t;        // 0..1279
        out[3 + i] = (float)vid[cross[i]];
    }
}

extern "C" void kernel_launch(void* const* d_in, const int* in_sizes, int n_in,
                              void* d_out, int out_size, void* d_ws, size_t ws_size,
                              hipStream_t stream) {
    const float* feature      = (const float*)d_in[0];
    const float* text_feature = (const float*)d_in[1];
    const float* centers      = (const float*)d_in[2];
    const int*   position     = (const int*)d_in[3];
    const int*   cross        = (const int*)d_in[4];
    const int*   vid          = (const int*)d_in[5];
    float* out = (float*)d_out;

    // workspace layout (floats)
    float* ws      = (float*)d_ws;
    float* img     = ws;                                  // P*B*D
    float* txt     = img + (size_t)P_ * B_ * D_;          // P*B*D
    float* fn2     = txt + (size_t)P_ * B_ * D_;          // P*B
    float* img_sim = fn2 + P_ * B_;                       // P*B*B
    float* txt_sim = img_sim + P_ * B_ * B_;              // P*B*B
    float* validf  = txt_sim + P_ * B_ * B_;              // P*B
    float* klrow   = validf + P_ * B_;                    // P*B
    float* xarr    = klrow + P_ * B_;                     // P*B
    float* maskf   = xarr + P_ * B_;                      // N
    float* diff    = maskf + N_;                          // P*B
    float* Spart   = diff + P_ * B_;                      // P*B*NT2

    mask_init_kernel<<<N_ / 256, 256, 0, stream>>>(maskf);
    mask_zero_kernel<<<(B_ * K_ + B_ + 255) / 256, 256, 0, stream>>>(cross, position, maskf);
    norm_kernel<<<dim3(P_ * B_, 2), 256, 0, stream>>>(feature, text_feature, img, txt, fn2);
    sim_kernel<<<dim3(P_, B_ / 2), 128, 0, stream>>>(img, txt, img_sim, txt_sim, validf);
    kl_kernel<<<dim3(P_, B_ / 4), 256, 0, stream>>>(img_sim, txt_sim, validf, klrow);
    posx_kernel<<<P_ * B_, 64, 0, stream>>>(feature, centers, fn2, cross, xarr);
    neg_mfma_kernel<<<dim3(NT2, P_), 256, 0, stream>>>(feature, centers, fn2, maskf, Spart);
    red_kernel<<<P_ * B_, 128, 0, stream>>>(Spart, xarr, diff);
    final_kernel<<<1, 128, 0, stream>>>(validf, klrow, diff, cross, vid, out);
}